// Round 15
// baseline (36.081 us; speedup 1.0000x reference)
//
#include <hip/hip_runtime.h>

#define BATCH 2048
#define NTRI 165
#define NPAIR 45
#define NSTEP 14
#define UCHUNKS (NSTEP * 3 * 64)   // 2688 16B chunks = 43008 B

typedef __attribute__((ext_vector_type(8))) short s16x8;
typedef __attribute__((ext_vector_type(16))) float f32x16;
typedef __attribute__((ext_vector_type(4))) int i32x4;

// ---- compile-time tables ----
struct TriTab { unsigned char a[NTRI], b[NTRI], c[NTRI]; };
constexpr TriTab make_tri() {
  TriTab t{}; int q = 0;
  for (int a = 0; a < 9; a++) for (int b = a; b < 9; b++) for (int c = b; c < 9; c++) {
    t.a[q] = (unsigned char)a; t.b[q] = (unsigned char)b; t.c[q] = (unsigned char)c; q++;
  }
  return t;
}
constexpr TriTab TRI = make_tri();

struct PairTab { unsigned char a[NPAIR], b[NPAIR]; };
constexpr PairTab make_pair() {
  PairTab t{}; int q = 0;
  for (int a = 0; a < 9; a++) for (int b = a; b < 9; b++) {
    t.a[q] = (unsigned char)a; t.b[q] = (unsigned char)b; q++;
  }
  return t;
}
constexpr PairTab PAIR = make_pair();

// ---- prep: build bf16 U^T table in A-fragment-major order ----
__global__ void prep_kernel(const float* __restrict__ U30, const float* __restrict__ U20, const float* __restrict__ U10,
                            const float* __restrict__ U31, const float* __restrict__ U21, const float* __restrict__ U11,
                            const float* __restrict__ U32, const float* __restrict__ U22, const float* __restrict__ U12,
                            unsigned short* __restrict__ wsB) {
  int t = blockIdx.x * blockDim.x + threadIdx.x;
  if (t >= UCHUNKS * 8) return;
  int j = t & 7;
  int lane = (t >> 3) & 63;
  int cf = t >> 9;                 // s*3+ct, 0..41
  int s = cf / 3, ct = cf % 3;
  int n = ct * 32 + (lane & 31);
  int k = s * 16 + (lane >> 5) * 8 + j;
  const float* U3[3] = {U30, U31, U32};
  const float* U2[3] = {U20, U21, U22};
  const float* U1[3] = {U10, U11, U12};
  float val = 0.f;
  if (n < 54) {
    if (k < NTRI) {
      int o = n / 6, j3 = n % 6;
      int ir = (o > 0) + (o > 3); int lo = o - (ir == 1 ? 1 : (ir == 2 ? 4 : 0));
      int a = TRI.a[k], b = TRI.b[k], cc = TRI.c[k];
      int pm[6][3] = {{a,b,cc},{a,cc,b},{b,a,cc},{b,cc,a},{cc,a,b},{cc,b,a}};
      for (int p = 0; p < 6; p++) {
        bool dup = false;
        for (int rr = 0; rr < p; rr++)
          if (pm[rr][0] == pm[p][0] && pm[rr][1] == pm[p][1] && pm[rr][2] == pm[p][2]) dup = true;
        if (!dup) val += U3[ir][(((lo * 9 + pm[p][0]) * 9 + pm[p][1]) * 9 + pm[p][2]) * 6 + j3];
      }
    }
  } else if (n < 81) {
    if (k >= NTRI && k < NTRI + NPAIR) {
      int o = (n - 54) / 3, j2 = (n - 54) % 3;
      int ir = (o > 0) + (o > 3); int lo = o - (ir == 1 ? 1 : (ir == 2 ? 4 : 0));
      int p = k - NTRI;
      int a = PAIR.a[p], b = PAIR.b[p];
      val = U2[ir][((lo * 9 + a) * 9 + b) * 3 + j2];
      if (a != b) val += U2[ir][((lo * 9 + b) * 9 + a) * 3 + j2];
    }
  } else if (n < 90) {
    if (k >= 210 && k < 219) {
      int o = n - 81;
      int ir = (o > 0) + (o > 3); int lo = o - (ir == 1 ? 1 : (ir == 2 ? 4 : 0));
      val = U1[ir][lo * 9 + (k - 210)];
    }
  }
  unsigned u = __float_as_uint(val);
  unsigned r = (u + 0x7FFFu + ((u >> 16) & 1u)) >> 16;   // RNE to bf16
  wsB[t] = (unsigned short)r;
}

// ---- compile-time monomial: no arrays, no alloca, nothing to demote to LDS ----
template<int K>
__device__ __forceinline__ float mono(const float* xx) {
  if constexpr (K < NTRI)              return xx[TRI.a[K]] * xx[TRI.b[K]] * xx[TRI.c[K]];
  else if constexpr (K < NTRI + NPAIR) return xx[PAIR.a[K - NTRI]] * xx[PAIR.b[K - NTRI]];
  else if constexpr (K < 219)          return xx[K - 210];
  else                                 return 0.f;
}

template<int S>
__device__ __forceinline__ s16x8 makeB(const float* xx, const int g2) {
  unsigned q0, q1, q2, q3;
  {
    float lo = g2 ? mono<S*16+8>(xx)  : mono<S*16+0>(xx);
    float hi = g2 ? mono<S*16+9>(xx)  : mono<S*16+1>(xx);
    asm("v_cvt_pk_bf16_f32 %0, %1, %2" : "=v"(q0) : "v"(lo), "v"(hi));
  }
  {
    float lo = g2 ? mono<S*16+10>(xx) : mono<S*16+2>(xx);
    float hi = g2 ? mono<S*16+11>(xx) : mono<S*16+3>(xx);
    asm("v_cvt_pk_bf16_f32 %0, %1, %2" : "=v"(q1) : "v"(lo), "v"(hi));
  }
  {
    float lo = g2 ? mono<S*16+12>(xx) : mono<S*16+4>(xx);
    float hi = g2 ? mono<S*16+13>(xx) : mono<S*16+5>(xx);
    asm("v_cvt_pk_bf16_f32 %0, %1, %2" : "=v"(q2) : "v"(lo), "v"(hi));
  }
  {
    float lo = g2 ? mono<S*16+14>(xx) : mono<S*16+6>(xx);
    float hi = g2 ? mono<S*16+15>(xx) : mono<S*16+7>(xx);
    asm("v_cvt_pk_bf16_f32 %0, %1, %2" : "=v"(q3) : "v"(lo), "v"(hi));
  }
  i32x4 bi;
  bi[0] = (int)q0; bi[1] = (int)q1; bi[2] = (int)q2; bi[3] = (int)q3;
  return __builtin_bit_cast(s16x8, bi);
}

// ---- 2-step pipelined k-chain, 2 batch rows sharing each U chunk ----
template<int S>
__device__ __forceinline__ void pipe(const float* xx0, const float* xx1, const int g2,
                                     const i32x4* Uf, const int l,
                                     f32x16& a00, f32x16& a01, f32x16& a02,
                                     f32x16& a10, f32x16& a11, f32x16& a12,
                                     i32x4 c0, i32x4 c1, i32x4 c2,      // chunks for step S
                                     i32x4 n0, i32x4 n1, i32x4 n2) {    // chunks for step S+1
  i32x4 f0{}, f1{}, f2{};
  if constexpr (S + 2 < NSTEP) {     // issue S+2 loads before the VALU/MFMA body
    f0 = Uf[((S + 2) * 3 + 0) * 64 + l];
    f1 = Uf[((S + 2) * 3 + 1) * 64 + l];
    f2 = Uf[((S + 2) * 3 + 2) * 64 + l];
  }
  s16x8 bf0 = makeB<S>(xx0, g2);
  s16x8 bf1 = makeB<S>(xx1, g2);
  s16x8 u0 = __builtin_bit_cast(s16x8, c0);
  s16x8 u1 = __builtin_bit_cast(s16x8, c1);
  s16x8 u2 = __builtin_bit_cast(s16x8, c2);
  a00 = __builtin_amdgcn_mfma_f32_32x32x16_bf16(u0, bf0, a00, 0, 0, 0);
  a10 = __builtin_amdgcn_mfma_f32_32x32x16_bf16(u0, bf1, a10, 0, 0, 0);
  a01 = __builtin_amdgcn_mfma_f32_32x32x16_bf16(u1, bf0, a01, 0, 0, 0);
  a11 = __builtin_amdgcn_mfma_f32_32x32x16_bf16(u1, bf1, a11, 0, 0, 0);
  a02 = __builtin_amdgcn_mfma_f32_32x32x16_bf16(u2, bf0, a02, 0, 0, 0);
  a12 = __builtin_amdgcn_mfma_f32_32x32x16_bf16(u2, bf1, a12, 0, 0, 0);
  if constexpr (S + 1 < NSTEP)
    pipe<S + 1>(xx0, xx1, g2, Uf, l, a00, a01, a02, a10, a11, a12, n0, n1, n2, f0, f1, f2);
}

// ---- main: 1024 blocks x 256 threads, 2 batch rows/block, zero LDS ----
__global__ __launch_bounds__(256) void symcon_mfma(
    const float* __restrict__ x, const int* __restrict__ indices,
    const float* __restrict__ w, const unsigned short* __restrict__ wsB,
    float* __restrict__ out)
{
  const int tid = threadIdx.x;
  const int wave = tid >> 6;
  const int l = tid & 63;
  const int l5 = l & 31;
  const int g2 = l >> 5;

  const int b0 = blockIdx.x * 2;
  const int b1 = b0 + 1;
  const int c = wave * 32 + l5;                  // 0..127

  float xx0[9], xx1[9];
  {
    const float* xp0 = x + ((size_t)b0 * 128 + c) * 9;
    const float* xp1 = x + ((size_t)b1 * 128 + c) * 9;
#pragma unroll
    for (int i = 0; i < 9; i++) { xx0[i] = xp0[i]; xx1[i] = xp1[i]; }
  }

  const int e0 = indices[b0];
  const int e1 = indices[b1];

  f32x16 a00, a01, a02, a10, a11, a12;
#pragma unroll
  for (int i = 0; i < 16; i++) {
    a00[i] = 0.f; a01[i] = 0.f; a02[i] = 0.f;
    a10[i] = 0.f; a11[i] = 0.f; a12[i] = 0.f;
  }

  const i32x4* Uf = (const i32x4*)wsB;
  i32x4 p0 = Uf[0 * 64 + l], p1 = Uf[1 * 64 + l], p2 = Uf[2 * 64 + l];
  i32x4 r0 = Uf[3 * 64 + l], r1 = Uf[4 * 64 + l], r2 = Uf[5 * 64 + l];
  pipe<0>(xx0, xx1, g2, Uf, l, a00, a01, a02, a10, a11, a12, p0, p1, p2, r0, r1, r2);

  // ---- epilogue per row (R5-validated mapping), sequential so wv isn't doubled ----
#pragma unroll
  for (int row = 0; row < 2; row++) {
    const int b = row ? b1 : b0;
    const int e = row ? e1 : e0;
    const float* wbase = w + (size_t)e * 30 * 128 + c;
    float wv[30];
#pragma unroll
    for (int p = 0; p < 30; p++) wv[p] = wbase[p * 128];

    float* orow = out + (size_t)b * 1152;
#pragma unroll
    for (int o = 0; o < 9; o++) {
      const int ir = (o > 0) + (o > 3);
      float p0f = 0.f, p1f = 0.f;
#pragma unroll
      for (int k3 = 0; k3 < 6; k3++) {
        const int n = 6 * o + k3;
        const int nl = n & 31, ct = n >> 5;
        const int reg = (nl & 3) + 4 * (nl >> 3);
        const float av = row ? (ct == 0 ? a10[reg] : ct == 1 ? a11[reg] : a12[reg])
                             : (ct == 0 ? a00[reg] : ct == 1 ? a01[reg] : a02[reg]);
        const float cf = wv[ir * 10 + k3];
        if (((nl >> 2) & 1) == 0) p0f = fmaf(av, cf, p0f);
        else                      p1f = fmaf(av, cf, p1f);
      }
#pragma unroll
      for (int k2 = 0; k2 < 3; k2++) {
        const int n = 54 + 3 * o + k2;
        const int nl = n & 31, ct = n >> 5;
        const int reg = (nl & 3) + 4 * (nl >> 3);
        const float av = row ? (ct == 0 ? a10[reg] : ct == 1 ? a11[reg] : a12[reg])
                             : (ct == 0 ? a00[reg] : ct == 1 ? a01[reg] : a02[reg]);
        const float cf = wv[ir * 10 + 6 + k2];
        if (((nl >> 2) & 1) == 0) p0f = fmaf(av, cf, p0f);
        else                      p1f = fmaf(av, cf, p1f);
      }
      {
        const int n = 81 + o;
        const int nl = n & 31, ct = n >> 5;
        const int reg = (nl & 3) + 4 * (nl >> 3);
        const float av = row ? (ct == 0 ? a10[reg] : ct == 1 ? a11[reg] : a12[reg])
                             : (ct == 0 ? a00[reg] : ct == 1 ? a01[reg] : a02[reg]);
        const float cf = wv[ir * 10 + 9];
        if (((nl >> 2) & 1) == 0) p0f = fmaf(av, cf, p0f);
        else                      p1f = fmaf(av, cf, p1f);
      }
      float p = g2 ? p1f : p0f;
      p += __shfl_xor(p, 32);
      const int col = (o == 0) ? c : (o < 4 ? 128 + 3 * c + (o - 1) : 512 + 5 * c + (o - 4));
      const bool mine = (o < 5) ? (g2 == 0) : (g2 == 1);
      if (mine) orow[col] = p;
    }
  }
}

extern "C" void kernel_launch(void* const* d_in, const int* in_sizes, int n_in,
                              void* d_out, int out_size, void* d_ws, size_t ws_size,
                              hipStream_t stream) {
  const float* x   = (const float*)d_in[0];
  const int*   idx = (const int*)d_in[1];
  const float* w   = (const float*)d_in[2];
  const float* U30 = (const float*)d_in[3];
  const float* U20 = (const float*)d_in[4];
  const float* U10 = (const float*)d_in[5];
  const float* U31 = (const float*)d_in[6];
  const float* U21 = (const float*)d_in[7];
  const float* U11 = (const float*)d_in[8];
  const float* U32 = (const float*)d_in[9];
  const float* U22 = (const float*)d_in[10];
  const float* U12 = (const float*)d_in[11];
  unsigned short* wsB = (unsigned short*)d_ws;
  float* out = (float*)d_out;

  prep_kernel<<<(UCHUNKS * 8 + 255) / 256, 256, 0, stream>>>(U30, U20, U10, U31, U21, U11, U32, U22, U12, wsB);
  symcon_mfma<<<BATCH / 2, 256, 0, stream>>>(x, idx, w, wsB, out);
}